// Round 8
// baseline (664.648 us; speedup 1.0000x reference)
//
#include <hip/hip_runtime.h>
#include <hip/hip_bf16.h>
#include <math.h>

typedef __bf16 bf16;
typedef __bf16 bf16x4 __attribute__((ext_vector_type(4)));
typedef __bf16 bf16x8 __attribute__((ext_vector_type(8)));
typedef float f32x4 __attribute__((ext_vector_type(4)));

#define GLB __attribute__((address_space(1)))
#define LDSAS __attribute__((address_space(3)))

// ---------------------------------------------------------------------------
// Dtype probe: flag=1 if d_in[0] is genuine fp32, 0 if packed bf16.
// ---------------------------------------------------------------------------
__global__ void probe_dtype(const unsigned int* __restrict__ X, int* __restrict__ flag) {
  int t = threadIdx.x;
  int cnt = 0;
  for (int i = t; i < 512; i += 64) {
    unsigned int e = (X[i] >> 7) & 0xFF;
    cnt += (e >= 110 && e <= 135) ? 1 : 0;
  }
#pragma unroll
  for (int off = 32; off > 0; off >>= 1) cnt += __shfl_down(cnt, off, 64);
  if (t == 0) flag[0] = (cnt < 256) ? 1 : 0;
}

// ---------------------------------------------------------------------------
// Prep v3: transpose+cast weights, cast X, and cos/sin table
//   tab[s*64+i] = {cos,sin}(pos[s] * 10000^(-i/64)), float2, 1 MiB.
//   Blocks: 0..10239 weights, 10240..18431 X-cast, 18432..18943 table.
// ---------------------------------------------------------------------------
__global__ void prep_weights(const void* __restrict__ Wq, const void* __restrict__ Wk,
                             const void* __restrict__ Wv, const void* __restrict__ Wo,
                             const void* __restrict__ X, const int* __restrict__ pos,
                             bf16* __restrict__ Wqkvt, bf16* __restrict__ Wot,
                             bf16* __restrict__ Xb, float2* __restrict__ tab,
                             const int* __restrict__ flag) {
  const int f = flag[0];
  const int t = threadIdx.x;  // 256 flat
  int b = blockIdx.x;
  __shared__ __attribute__((aligned(16))) bf16 tileT[64][72];
  const void* W;
  bf16* out;
  int N, bx, by;
  if (b < 4096) {                        // Wq [4096][4096]
    W = Wq; out = Wqkvt; N = 4096; bx = b & 63; by = b >> 6;
  } else if (b < 5120) {                 // Wk [4096][1024]
    b -= 4096; W = Wk; out = Wqkvt + (size_t)4096 * 4096; N = 1024; bx = b & 15; by = b >> 4;
  } else if (b < 6144) {                 // Wv [4096][1024]
    b -= 5120; W = Wv; out = Wqkvt + (size_t)5120 * 4096; N = 1024; bx = b & 15; by = b >> 4;
  } else if (b < 10240) {                // Wo [4096][4096]
    b -= 6144; W = Wo; out = Wot; N = 4096; bx = b & 63; by = b >> 6;
  } else if (b < 18432) {                // X cast [2048][4096]
    b -= 10240;
    const size_t i = ((size_t)b * 256 + t) * 4;
    bf16x4 o;
    if (f) {
      const float4 v = *(const float4*)((const float*)X + i);
      o[0] = (bf16)v.x; o[1] = (bf16)v.y; o[2] = (bf16)v.z; o[3] = (bf16)v.w;
    } else {
      o = *(const bf16x4*)((const bf16*)X + i);
    }
    *(bf16x4*)&Xb[i] = o;
    return;
  } else {                               // RoPE cos/sin table, 512 blocks
    b -= 18432;
    const int i = t & 63;
    const int s = b * 4 + (t >> 6);
    const float p = (float)pos[s];
    const float inv = exp2f((float)i * -0.2076205088f);  // 10000^(-i/64)
    float sn, cs;
    sincosf(p * inv, &sn, &cs);
    tab[s * 64 + i] = make_float2(cs, sn);
    return;
  }
  const int n0 = bx * 64, k0 = by * 64;

  const int rr = t >> 4, cc = (t & 15) * 4;
  const int s_in = (t & 15) >> 1;
#pragma unroll
  for (int p = 0; p < 4; ++p) {
    const int r = p * 16 + rr;
    bf16 vals[4];
    if (f) {
      const float4 v = *(const float4*)((const float*)W + (size_t)(k0 + r) * N + n0 + cc);
      vals[0] = (bf16)v.x; vals[1] = (bf16)v.y; vals[2] = (bf16)v.z; vals[3] = (bf16)v.w;
    } else {
      const bf16x4 v = *(const bf16x4*)((const bf16*)W + (size_t)(k0 + r) * N + n0 + cc);
#pragma unroll
      for (int u = 0; u < 4; ++u) vals[u] = v[u];
    }
    const int idx = (((r >> 3) ^ s_in) << 3) + (r & 7);
#pragma unroll
    for (int u = 0; u < 4; ++u) tileT[cc + u][idx] = vals[u];
  }
  __syncthreads();

  const int nn = t >> 3, c8 = t & 7;
#pragma unroll
  for (int p = 0; p < 2; ++p) {
    const int n = p * 32 + nn;
    const int s = (n >> 3) & 7;
    const bf16x8 v = *(const bf16x8*)&tileT[n][(c8 ^ s) * 8];
    *(bf16x8*)&out[(size_t)(n0 + n) * 4096 + k0 + c8 * 8] = v;
  }
}

// ---------------------------------------------------------------------------
// gemm_bt v3: BK=64 (round-6 verified) + in-register RoPE epilogue.
//   B-col remap: wave col = ni*32 + wcol*16 + n16 (was wcol*64 + ni*16 + n16).
//   Each lane then holds col pairs (c, c+64) in acc[ni] and acc[ni+2] -> the
//   RoPE rotate pair is lane-local: rotate on f32 acc before quantization
//   using the prepped cos/sin table. No extra LDS, no extra barriers.
//   LDS swizzle unchanged: rowb&7 == n16&7 under the remap.
//   Blocks with blockIdx.x < rope_nbx (=40 for QKV: Q+K heads) apply RoPE;
//   V cols (bx>=40) and the out-proj call (rope_nbx=0) write plain.
// ---------------------------------------------------------------------------
__global__ __launch_bounds__(256, 2) void gemm_bt(
    const bf16* __restrict__ A, const bf16* __restrict__ Bt,
    void* __restrict__ C, const int* __restrict__ flagp, int M, int N, int K,
    const float2* __restrict__ tab, int rope_nbx) {
  __shared__ bf16 As[128 * 64];
  __shared__ bf16 Bs[128 * 64];
  const int t = threadIdx.x;
  const int m0 = blockIdx.y * 128, n0 = blockIdx.x * 128;
  const int lane = t & 63, n16 = lane & 15, quad = lane >> 4;
  const int w = t >> 6, wrow = w >> 1, wcol = w & 1;

  f32x4 acc[4][4] = {};
  const int rA = t >> 3;
  const int colA = ((t & 7) ^ (rA & 7)) * 8;

  for (int k0 = 0; k0 < K; k0 += 64) {
#pragma unroll
    for (int i = 0; i < 4; ++i) {
      const int elem = i * 2048 + t * 8;
      const int row = i * 32 + rA;
      __builtin_amdgcn_global_load_lds(
          (const GLB void*)(A + (size_t)(m0 + row) * K + k0 + colA),
          (LDSAS void*)(&As[elem]), 16, 0, 0);
      __builtin_amdgcn_global_load_lds(
          (const GLB void*)(Bt + (size_t)(n0 + row) * K + k0 + colA),
          (LDSAS void*)(&Bs[elem]), 16, 0, 0);
    }
    __syncthreads();
#pragma unroll
    for (int kk = 0; kk < 2; ++kk) {
      bf16x8 af[4], bfr[4];
#pragma unroll
      for (int i = 0; i < 4; ++i) {
        const int rowa = wrow * 64 + i * 16 + n16;
        af[i] = *(const bf16x8*)&As[rowa * 64 + (((kk * 4 + quad) ^ (rowa & 7)) * 8)];
        const int rowb = i * 32 + wcol * 16 + n16;   // remapped B col
        bfr[i] = *(const bf16x8*)&Bs[rowb * 64 + (((kk * 4 + quad) ^ (rowb & 7)) * 8)];
      }
#pragma unroll
      for (int mi = 0; mi < 4; ++mi)
#pragma unroll
        for (int ni = 0; ni < 4; ++ni)
          acc[mi][ni] = __builtin_amdgcn_mfma_f32_16x16x32_bf16(
              af[mi], bfr[ni], acc[mi][ni], 0, 0, 0);
    }
    __syncthreads();
  }

  // ---- in-register RoPE on (ni, ni+2) col pairs
  if (blockIdx.x < rope_nbx) {
    const int i1 = wcol * 16 + n16;  // 0..31; pair cols (i1, i1+64),(i1+32,i1+96)
#pragma unroll
    for (int mi = 0; mi < 4; ++mi) {
      const int r0 = m0 + wrow * 64 + mi * 16 + quad * 4;
#pragma unroll
      for (int r = 0; r < 4; ++r) {
        const int s = r0 + r;
        const float2 cs1 = tab[s * 64 + i1];
        const float2 cs2 = tab[s * 64 + i1 + 32];
        const float a0 = acc[mi][0][r], a1 = acc[mi][1][r];
        const float a2 = acc[mi][2][r], a3 = acc[mi][3][r];
        acc[mi][0][r] = a0 * cs1.x - a2 * cs1.y;
        acc[mi][2][r] = a2 * cs1.x + a0 * cs1.y;
        acc[mi][1][r] = a1 * cs2.x - a3 * cs2.y;
        acc[mi][3][r] = a3 * cs2.x + a1 * cs2.y;
      }
    }
  }

  const bool f32out = (flagp != nullptr) && (flagp[0] != 0);
  if (f32out) {
    float* Cf = (float*)C;
#pragma unroll
    for (int mi = 0; mi < 4; ++mi)
#pragma unroll
      for (int ni = 0; ni < 4; ++ni) {
        const int r0 = m0 + wrow * 64 + mi * 16 + quad * 4;
        const int c = n0 + ni * 32 + wcol * 16 + n16;
#pragma unroll
        for (int r = 0; r < 4; ++r) Cf[(size_t)(r0 + r) * N + c] = acc[mi][ni][r];
      }
  } else {
    bf16* Cb = (bf16*)C;
#pragma unroll
    for (int mi = 0; mi < 4; ++mi)
#pragma unroll
      for (int ni = 0; ni < 4; ++ni) {
        const int r0 = m0 + wrow * 64 + mi * 16 + quad * 4;
        const int c = n0 + ni * 32 + wcol * 16 + n16;
#pragma unroll
        for (int r = 0; r < 4; ++r) Cb[(size_t)(r0 + r) * N + c] = (bf16)acc[mi][ni][r];
      }
  }
}

// ---------------------------------------------------------------------------
// V transpose only (RoPE now fused into the QKV GEMM epilogue).
//   [2048 s][1024 v] (stride 6144, offset 5120) -> Vt[v][s]. 2048 blocks.
// ---------------------------------------------------------------------------
__global__ void vt_kern(const bf16* __restrict__ QKV, bf16* __restrict__ Vt) {
  const int t = threadIdx.x;
  const int b = blockIdx.x;
  __shared__ bf16 tile[32][34];
  const int tx = t & 31, ty = t >> 5;
  const int v0 = (b & 31) * 32, s0 = (b >> 5) * 32;
#pragma unroll
  for (int j = 0; j < 4; ++j)
    tile[ty + j * 8][tx] = QKV[(size_t)(s0 + ty + j * 8) * 6144 + 5120 + v0 + tx];
  __syncthreads();
#pragma unroll
  for (int j = 0; j < 4; ++j)
    Vt[(size_t)(v0 + ty + j * 8) * 2048 + s0 + tx] = tile[tx][ty + j * 8];
}

// ---------------------------------------------------------------------------
// Flash attention v8: staging-free, 1-wave blocks, barrier-free.
//   m169 lesson: K/V panels are L2-fit (per-XCD working set ~3MB < 4MB when
//   each XCD owns one hkv) -> LDS staging + double-buffer + ALL barriers
//   removed. K frags load direct from QKV, V frags direct from Vt_g, at the
//   same logical offsets v6 read from LDS. Ps is wave-private (lgkm-ordered).
//   Grid: 2048 blocks x 64 threads = 8 waves/CU; bid -> (xcd, j, pairp, wsub)
//   with h = xcd*4 + j  =>  hkv == xcd (each XCD L2 caches exactly its panel).
// ---------------------------------------------------------------------------
__global__ __launch_bounds__(64) void flash_attn(
    const bf16* __restrict__ QKV, const bf16* __restrict__ Vt_g,
    bf16* __restrict__ O) {
  __shared__ bf16 Ps[16 * 72];
  const int bid = blockIdx.x;
  const int xcd = bid & 7;
  const int idx = bid >> 3;            // 0..255
  const int h = xcd * 4 + (idx >> 6);  // hkv == xcd
  const int pairp = (idx >> 2) & 15;
  const int wsub = idx & 3;
  const int hkv = h >> 2;
  const int t = threadIdx.x;
  const int n16 = t & 15, quad = t >> 4;
  const bf16* Qp = QKV + h * 128;
  const bf16* Kp = QKV + 4096 + hkv * 128;
  const bf16* Vp = Vt_g + (size_t)hkv * 128 * 2048;

  for (int pass = 0; pass < 2; ++pass) {
    const int qt = (pass == 0) ? pairp : 31 - pairp;
    const int qloc = wsub * 16 + n16;
    bf16x8 qa[4];
    {
      const bf16* qrow = Qp + (size_t)(qt * 64 + qloc) * 6144 + quad * 8;
#pragma unroll
      for (int kf = 0; kf < 4; ++kf) qa[kf] = *(const bf16x8*)(qrow + kf * 32);
    }
    f32x4 o[8] = {};
    float l_ = 0.f;

    for (int kt = 0; kt <= qt; ++kt) {
      const bf16* Kt = Kp + (size_t)(kt * 64) * 6144;
      const bf16* Vt = Vp + kt * 64;
      const bool diag = (kt == qt);
      // ---- S^T = (K Q^T)/sqrt(D); lane: q = qloc, kv = ns*16+quad*4+r
#pragma unroll
      for (int ns = 0; ns < 4; ++ns) {
        f32x4 c = {};
#pragma unroll
        for (int kf = 0; kf < 4; ++kf)
          c = __builtin_amdgcn_mfma_f32_16x16x32_bf16(
              *(const bf16x8*)(Kt + (size_t)(ns * 16 + n16) * 6144 +
                               (kf * 4 + quad) * 8),
              qa[kf], c, 0, 0, 0);
        float p[4];
        if (diag) {
          const int kv0 = ns * 16 + quad * 4;
#pragma unroll
          for (int r = 0; r < 4; ++r)
            p[r] = (kv0 + r > qloc)
                       ? 0.f
                       : __expf(fminf(c[r] * 0.08838834764831845f, 60.f));
        } else {
#pragma unroll
          for (int r = 0; r < 4; ++r)
            p[r] = __expf(fminf(c[r] * 0.08838834764831845f, 60.f));
        }
        l_ += (p[0] + p[1]) + (p[2] + p[3]);
        bf16x4 pb;
#pragma unroll
        for (int r = 0; r < 4; ++r) pb[r] = (bf16)p[r];
        *(bf16x4*)&Ps[n16 * 72 + ns * 16 + quad * 4] = pb;
      }
      // ---- O += P V (wave-private Ps; lgkmcnt ordering only, no barrier)
      const bf16x8 a0 = *(const bf16x8*)&Ps[n16 * 72 + quad * 8];
      const bf16x8 a1 = *(const bf16x8*)&Ps[n16 * 72 + 32 + quad * 8];
#pragma unroll
      for (int dt = 0; dt < 8; ++dt) {
        const bf16* vr = Vt + (size_t)(dt * 16 + n16) * 2048;
        const bf16x8 b0 = *(const bf16x8*)(vr + quad * 8);
        o[dt] = __builtin_amdgcn_mfma_f32_16x16x32_bf16(a0, b0, o[dt], 0, 0, 0);
        const bf16x8 b1 = *(const bf16x8*)(vr + 32 + quad * 8);
        o[dt] = __builtin_amdgcn_mfma_f32_16x16x32_bf16(a1, b1, o[dt], 0, 0, 0);
      }
    }
    // ---- l: reduce across quads (lanes with same n16 hold same q)
    l_ += __shfl_xor(l_, 16, 64);
    l_ += __shfl_xor(l_, 32, 64);
    float linv[4];
#pragma unroll
    for (int r = 0; r < 4; ++r) linv[r] = 1.f / __shfl(l_, quad * 4 + r, 64);
#pragma unroll
    for (int dt = 0; dt < 8; ++dt)
#pragma unroll
      for (int r = 0; r < 4; ++r) {
        const int qi = qt * 64 + wsub * 16 + quad * 4 + r;
        O[(size_t)qi * 4096 + h * 128 + dt * 16 + n16] = (bf16)(o[dt][r] * linv[r]);
      }
  }
}

// ---------------------------------------------------------------------------
extern "C" void kernel_launch(void* const* d_in, const int* in_sizes, int n_in,
                              void* d_out, int out_size, void* d_ws, size_t ws_size,
                              hipStream_t stream) {
  (void)in_sizes; (void)n_in; (void)out_size; (void)ws_size;
  const void* X = d_in[0];
  const int* pos = (const int*)d_in[1];
  const void* Wq = d_in[2];
  const void* Wk = d_in[3];
  const void* Wv = d_in[4];
  const void* Wo = d_in[5];

  char* ws = (char*)d_ws;
  const size_t MB = 1ull << 20;
  int* flag     = (int*)(ws + 0);
  bf16* Xb      = (bf16*)(ws + 1 * MB);    // 16 MiB (aliased by attn later)
  bf16* attn    = (bf16*)(ws + 1 * MB);    // alias: Xb dead after QKV GEMM
  bf16* Wqkvt   = (bf16*)(ws + 17 * MB);   // [6144][4096] = 48 MiB
  bf16* Wot     = (bf16*)(ws + 65 * MB);   // 32 MiB
  bf16* QKV     = (bf16*)(ws + 97 * MB);   // [2048][6144] = 24 MiB
  bf16* Vt_g    = (bf16*)(ws + 121 * MB);  // [1024][2048] = 4 MiB -> 125 MiB
  // tab ALIASES Vt_g's first MiB: tab is written in prep, read only by the
  // QKV GEMM epilogue, and dead before vt_kern overwrites the region.
  // Keeps total footprint at the proven 125 MiB (126 MiB suspect in r7 fail).
  float2* tab   = (float2*)(ws + 121 * MB); // [2048][64] float2 = 1 MiB

  probe_dtype<<<1, 64, 0, stream>>>((const unsigned int*)X, flag);

  // weights + X-cast + RoPE table
  prep_weights<<<18944, 256, 0, stream>>>(Wq, Wk, Wv, Wo, X, pos,
                                          Wqkvt, Wot, Xb, tab, flag);

  // fused QKV projection + in-register RoPE on Q/K heads (bx<40)
  gemm_bt<<<dim3(48, 16), 256, 0, stream>>>(Xb, Wqkvt, QKV, nullptr,
                                            2048, 6144, 4096, tab, 40);

  vt_kern<<<2048, 256, 0, stream>>>(QKV, Vt_g);  // V^T only (tab now dead)

  flash_attn<<<2048, 64, 0, stream>>>(QKV, Vt_g, attn);

  gemm_bt<<<dim3(32, 16), 256, 0, stream>>>(attn, Wot, d_out, flag,
                                            2048, 4096, 4096, tab, 0);
}